// Round 10
// baseline (96.831 us; speedup 1.0000x reference)
//
#include <hip/hip_runtime.h>
#include <hip/hip_bf16.h>

#ifndef __has_builtin
#define __has_builtin(x) 0
#endif

typedef __attribute__((ext_vector_type(8))) short short8;   // 8 bf16 = 4 VGPRs
typedef __attribute__((ext_vector_type(4))) float floatx4;  // MFMA C/D

__device__ __forceinline__ float fast_exp2(float x) {
#if __has_builtin(__builtin_amdgcn_exp2f)
    return __builtin_amdgcn_exp2f(x);   // CU-SHARED unit, ~12.5 cyc/wave64 (R1..R9 fit)
#else
    return exp2f(x);
#endif
}
__device__ __forceinline__ float fast_rcp(float x) {
#if __has_builtin(__builtin_amdgcn_rcpf)
    return __builtin_amdgcn_rcpf(x);
#else
    return 1.0f / x;
#endif
}

// exp2 from FULL-RATE main-pipe ops only (no v_exp/v_floor/v_cvt/v_ldexp —
// those serialize on the CU-shared / quarter-rate pipes; R6's regression).
// round via magic-add; 2^ri scale via integer shift of the magic mantissa:
// u = bits(t+1.5*2^23) = 0x4B400000 + ri  ->  (u<<23)+0x3F800000 = (127+ri)<<23
// (exact mod 2^32). deg-4 Taylor on f in [-0.5,0.5], rel err ~8e-5 << bf16.
// 11 full-rate insts ~= 22 cyc/wave64 on the PER-SIMD pipe.
__device__ __forceinline__ float poly_exp2(float t) {
    t = fmaxf(t, -110.0f);                     // guard bit-trick underflow wrap
    const float MAGIC = 12582912.0f;           // 1.5 * 2^23
    float z = t + MAGIC;                       // mantissa holds round(t)
    float r = z - MAGIC;                       // round(t) exactly
    float f = t - r;                           // [-0.5, 0.5], exact
    float p = fmaf(f, 0.00961812910762848f, 0.05550410866482158f);
    p = fmaf(f, p, 0.24022650695910072f);
    p = fmaf(f, p, 0.69314718055994531f);
    p = fmaf(f, p, 1.0f);                      // ~= 2^f
    unsigned u = __builtin_bit_cast(unsigned, z);
    unsigned sb = (u << 23) + 0x3F800000u;     // bits of 2^round(t)
    return p * __builtin_bit_cast(float, sb);
}

__device__ __forceinline__ unsigned short bf16_of(float v) {
    union { __hip_bfloat16 b; unsigned short s; } cv;
    cv.b = __float2bfloat16(v);
    return cv.s;
}
__device__ __forceinline__ float bf16_back(unsigned short s) {
    union { __hip_bfloat16 b; unsigned short t; } cv;
    cv.t = s;
    return __bfloat162float(cv.b);
}
__device__ __forceinline__ unsigned bcat(unsigned short lo, unsigned short hi) {
    return (unsigned)lo | ((unsigned)hi << 16);   // slot j even = low half
}
__device__ __forceinline__ unsigned pack_bf16(float a, float b) {
    __hip_bfloat162 h = __float22bfloat162_rn(make_float2(a, b));
    union { __hip_bfloat162 h2; unsigned u; } cv;
    cv.h2 = h;
    return cv.u;
}

#define VQ_K 256
#define BLK  256
#define T    2

// R10 = R9 structure (both GEMMs on MFMA, 13-slot error-compensated bf16
// split, pi-permutation baked into V'-frags, tables in d_ws, no LDS/barrier)
// + hybrid exp: 3 of 8 weights per group via v_exp_f32 (CU-shared unit,
// ~16us worth), 5 of 8 via poly_exp2 (per-SIMD main pipe, ~16us worth) —
// the two pipes now run in parallel instead of serializing on one.

// ---- pre-kernel: tables into d_ws ----
__global__ void vq_prep(const float* __restrict__ center, uint4* __restrict__ ws) {
    const float L2E = 1.4426950408889634f;
    int f = blockIdx.x * 256 + threadIdx.x;
    if (f < 1024) {
        int q = (f >> 4) & 3, ml = f & 15;
        int k = (f >> 6) * 16 + ml;
        float4 c = reinterpret_cast<const float4*>(center)[k];
        float s = 2.0f * L2E;
        float c2f[4] = {s * c.x, s * c.y, s * c.z, s * c.w};
        unsigned short ch[4], cl[4];
#pragma unroll
        for (int d = 0; d < 4; ++d) {
            ch[d] = bf16_of(c2f[d]);
            cl[d] = bf16_of(c2f[d] - bf16_back(ch[d]));
        }
        float b = -L2E * (c.x * c.x + c.y * c.y + c.z * c.z + c.w * c.w);
        unsigned short bh = bf16_of(b);
        unsigned short bl = bf16_of(b - bf16_back(bh));
        uint4 e;
        if (q == 0) {
            e.x = bcat(ch[0], ch[1]); e.y = bcat(ch[2], ch[3]);
            e.z = e.x;                e.w = e.y;           // d4-7 pair with xl
        } else if (q == 1) {
            e.x = bcat(cl[0], cl[1]); e.y = bcat(cl[2], cl[3]);
            e.z = bcat(bh, bl);       e.w = 0;             // d12=bh, d13=bl
        } else {
            e.x = e.y = e.z = e.w = 0;
        }
        ws[f] = e;
    } else {
        int g = f - 1024;                 // 0..511
        int c = g >> 6, q = (g >> 4) & 3, n = g & 15;
        unsigned rr[4];
#pragma unroll
        for (int r = 0; r < 4; ++r) {
            int j0 = 2 * r, j1 = 2 * r + 1;
            int k0 = 32 * c + (j0 < 4 ? 4 * q + j0 : 16 + 4 * q + j0 - 4);
            int k1 = 32 * c + (j1 < 4 ? 4 * q + j1 : 16 + 4 * q + j1 - 4);
            float v0 = (n < 4) ? center[k0 * 4 + n] : (n == 4 ? 1.f : 0.f);
            float v1 = (n < 4) ? center[k1 * 4 + n] : (n == 4 ? 1.f : 0.f);
            rr[r] = bcat(bf16_of(v0), bf16_of(v1));
        }
        ws[f] = make_uint4(rr[0], rr[1], rr[2], rr[3]);
    }
}

__global__ __launch_bounds__(BLK, 8) void vq_main(const float* __restrict__ x,
                                                  const uint4* __restrict__ ws,
                                                  float* __restrict__ out) {
    const int lane = threadIdx.x & 63;
    const int wv   = threadIdx.x >> 6;
    const int q    = lane >> 4;
    const int ml   = lane & 15;
    const int mbase = blockIdx.x * (4 * 16 * T) + wv * (16 * T);
    const float4* __restrict__ x4 = reinterpret_cast<const float4*>(x);
    const uint4* __restrict__ ta = ws;          // A-frags [kt*64+lane]
    const uint4* __restrict__ tv = ws + 1024;   // V'-frags [c*64+lane]

    union Frag { uint4 u4; unsigned u[4]; short8 v; };

    // ---- Xext B-frags: q0=[xh|xl], q1=[xh|1,1,0], q2/3=0 ----
    Frag B[T];
#pragma unroll
    for (int t = 0; t < T; ++t) {
        float4 xv = x4[mbase + t * 16 + ml];
        float xf[4] = {xv.x, xv.y, xv.z, xv.w};
        unsigned short xh[4], xl[4];
#pragma unroll
        for (int d = 0; d < 4; ++d) {
            xh[d] = bf16_of(xf[d]);
            xl[d] = bf16_of(xf[d] - bf16_back(xh[d]));
        }
        unsigned h01 = bcat(xh[0], xh[1]), h23 = bcat(xh[2], xh[3]);
        unsigned l01 = bcat(xl[0], xl[1]), l23 = bcat(xl[2], xl[3]);
        const unsigned ONE2 = 0x3F803F80u;      // {1.0bf16, 1.0bf16}
        B[t].u[0] = (q <= 1) ? h01 : 0;
        B[t].u[1] = (q <= 1) ? h23 : 0;
        B[t].u[2] = (q == 0) ? l01 : ((q == 1) ? ONE2 : 0);
        B[t].u[3] = (q == 0) ? l23 : 0;
    }

    floatx4 O[T];
#pragma unroll
    for (int t = 0; t < T; ++t) O[t] = (floatx4){0.f, 0.f, 0.f, 0.f};
    const floatx4 Z4 = (floatx4){0.f, 0.f, 0.f, 0.f};

    for (int c = 0; c < 8; ++c) {               // 32 centers per chunk
        Frag a0, a1, vf;
        a0.u4 = ta[(2 * c) * 64 + lane];        // coalesced 1KB/wave, L1-hot
        a1.u4 = ta[(2 * c + 1) * 64 + lane];
        vf.u4 = tv[c * 64 + lane];
#pragma unroll
        for (int t = 0; t < T; ++t) {
            floatx4 S0 = __builtin_amdgcn_mfma_f32_16x16x32_bf16(a0.v, B[t].v, Z4, 0, 0, 0);
            floatx4 S1 = __builtin_amdgcn_mfma_f32_16x16x32_bf16(a1.v, B[t].v, Z4, 0, 0, 0);
            // hybrid exp routing: 3 of 8 on the CU-shared trans unit,
            // 5 of 8 on the per-SIMD main pipe — pipes run in parallel.
            float e0 = fast_exp2(S0[0]);
            float e1 = poly_exp2(S0[1]);
            float e2 = poly_exp2(S0[2]);
            float e3 = fast_exp2(S0[3]);
            float e4 = poly_exp2(S1[0]);
            float e5 = fast_exp2(S1[1]);
            float e6 = poly_exp2(S1[2]);
            float e7 = poly_exp2(S1[3]);
            Frag p;
            p.u[0] = pack_bf16(e0, e1);
            p.u[1] = pack_bf16(e2, e3);
            p.u[2] = pack_bf16(e4, e5);
            p.u[3] = pack_bf16(e6, e7);
            O[t] = __builtin_amdgcn_mfma_f32_16x16x32_bf16(p.v, vf.v, O[t], 0, 0, 0);
        }
    }

    // ---- epilogue: D col n = lane&15, row m = q*4 + r; col 4 = denominator.
#pragma unroll
    for (int t = 0; t < T; ++t) {
#pragma unroll
        for (int r = 0; r < 4; ++r) {
            float den = __shfl(O[t][r], (lane & 48) + 4, 64);
            float val = O[t][r] * fast_rcp(den);
            int m = mbase + t * 16 + q * 4 + r;
            if (ml < 4) out[m * 4 + ml] = val;
        }
    }
}

extern "C" void kernel_launch(void* const* d_in, const int* in_sizes, int n_in,
                              void* d_out, int out_size, void* d_ws, size_t ws_size,
                              hipStream_t stream) {
    const float* x      = (const float*)d_in[0];   // [8, 262144] fp32
    const float* center = (const float*)d_in[1];   // [256, 4] fp32
    float* out = (float*)d_out;
    uint4* ws  = (uint4*)d_ws;                     // 1536 uint4 = 24 KB

    vq_prep<<<6, 256, 0, stream>>>(center, ws);

    int nvec   = in_sizes[0] / 4;                  // 524288 m-vectors
    int blocks = nvec / (4 * 16 * T);              // 4096
    vq_main<<<blocks, BLK, 0, stream>>>(x, ws, out);
}

// Round 11
// 91.639 us; speedup vs baseline: 1.0567x; 1.0567x over previous
//
#include <hip/hip_runtime.h>
#include <hip/hip_bf16.h>

#ifndef __has_builtin
#define __has_builtin(x) 0
#endif

typedef __attribute__((ext_vector_type(8))) short short8;   // 8 bf16 = 4 VGPRs
typedef __attribute__((ext_vector_type(4))) float floatx4;  // MFMA C/D

__device__ __forceinline__ float fast_exp2(float x) {
#if __has_builtin(__builtin_amdgcn_exp2f)
    return __builtin_amdgcn_exp2f(x);   // trans unit ~48cyc/wave64 occupancy (R1..R9 fit)
#else
    return exp2f(x);
#endif
}
__device__ __forceinline__ float fast_rcp(float x) {
#if __has_builtin(__builtin_amdgcn_rcpf)
    return __builtin_amdgcn_rcpf(x);
#else
    return 1.0f / x;
#endif
}

// exp2 from FULL-RATE main-pipe ops only. 9 insts, minimal live temps.
// No clamp: |t| <= ~90 by data bounds (|x|<=5.5, |c|<=4.5) — wrap needs t<-127.
// deg-3 minimax on [-0.5,0.5]: rel err ~2e-4 << bf16 ulp (0.4%).
__device__ __forceinline__ float poly_exp2(float t) {
    const float MAGIC = 12582912.0f;           // 1.5 * 2^23
    float z = t + MAGIC;                       // low mantissa = round(t)
    float f = t - (z - MAGIC);                 // [-0.5, 0.5], exact
    float p = fmaf(f, 0.0558087f, 0.2417676f);
    p = fmaf(f, p, 0.6931447f);
    p = fmaf(f, p, 1.0f);                      // ~= 2^f
    unsigned sb = (__builtin_bit_cast(unsigned, z) << 23) + 0x3F800000u;
    return p * __builtin_bit_cast(float, sb);  // * 2^round(t), exact
}

__device__ __forceinline__ unsigned short bf16_of(float v) {
    union { __hip_bfloat16 b; unsigned short s; } cv;
    cv.b = __float2bfloat16(v);
    return cv.s;
}
__device__ __forceinline__ float bf16_back(unsigned short s) {
    union { __hip_bfloat16 b; unsigned short t; } cv;
    cv.t = s;
    return __bfloat162float(cv.b);
}
__device__ __forceinline__ unsigned bcat(unsigned short lo, unsigned short hi) {
    return (unsigned)lo | ((unsigned)hi << 16);   // slot j even = low half
}
__device__ __forceinline__ unsigned pack_bf16(float a, float b) {
    __hip_bfloat162 h = __float22bfloat162_rn(make_float2(a, b));
    union { __hip_bfloat162 h2; unsigned u; } cv;
    cv.h2 = h;
    return cv.u;
}

#define VQ_K 256
#define BLK  256
#define T    2

// R11 = R10 hybrid (3/8 exps on trans unit, 5/8 on main-pipe poly) with the
// spill fixed: launch_bounds(256,6) caps VGPR at ~84 (R10's (256,8) cap=64 was
// below the poly loop's ~70-reg footprint -> scratch spills -> regression).

// ---- pre-kernel: fragment tables into d_ws (24 KB, L1-resident) ----
__global__ void vq_prep(const float* __restrict__ center, uint4* __restrict__ ws) {
    const float L2E = 1.4426950408889634f;
    int f = blockIdx.x * 256 + threadIdx.x;
    if (f < 1024) {
        int q = (f >> 4) & 3, ml = f & 15;
        int k = (f >> 6) * 16 + ml;
        float4 c = reinterpret_cast<const float4*>(center)[k];
        float s = 2.0f * L2E;
        float c2f[4] = {s * c.x, s * c.y, s * c.z, s * c.w};
        unsigned short ch[4], cl[4];
#pragma unroll
        for (int d = 0; d < 4; ++d) {
            ch[d] = bf16_of(c2f[d]);
            cl[d] = bf16_of(c2f[d] - bf16_back(ch[d]));
        }
        float b = -L2E * (c.x * c.x + c.y * c.y + c.z * c.z + c.w * c.w);
        unsigned short bh = bf16_of(b);
        unsigned short bl = bf16_of(b - bf16_back(bh));
        uint4 e;
        if (q == 0) {
            e.x = bcat(ch[0], ch[1]); e.y = bcat(ch[2], ch[3]);
            e.z = e.x;                e.w = e.y;           // d4-7 pair with xl
        } else if (q == 1) {
            e.x = bcat(cl[0], cl[1]); e.y = bcat(cl[2], cl[3]);
            e.z = bcat(bh, bl);       e.w = 0;             // d12=bh, d13=bl
        } else {
            e.x = e.y = e.z = e.w = 0;
        }
        ws[f] = e;
    } else {
        int g = f - 1024;                 // 0..511
        int c = g >> 6, q = (g >> 4) & 3, n = g & 15;
        unsigned rr[4];
#pragma unroll
        for (int r = 0; r < 4; ++r) {
            int j0 = 2 * r, j1 = 2 * r + 1;
            int k0 = 32 * c + (j0 < 4 ? 4 * q + j0 : 16 + 4 * q + j0 - 4);
            int k1 = 32 * c + (j1 < 4 ? 4 * q + j1 : 16 + 4 * q + j1 - 4);
            float v0 = (n < 4) ? center[k0 * 4 + n] : (n == 4 ? 1.f : 0.f);
            float v1 = (n < 4) ? center[k1 * 4 + n] : (n == 4 ? 1.f : 0.f);
            rr[r] = bcat(bf16_of(v0), bf16_of(v1));
        }
        ws[f] = make_uint4(rr[0], rr[1], rr[2], rr[3]);
    }
}

__global__ __launch_bounds__(BLK, 6) void vq_main(const float* __restrict__ x,
                                                  const uint4* __restrict__ ws,
                                                  float* __restrict__ out) {
    const int lane = threadIdx.x & 63;
    const int wv   = threadIdx.x >> 6;
    const int q    = lane >> 4;
    const int ml   = lane & 15;
    const int mbase = blockIdx.x * (4 * 16 * T) + wv * (16 * T);
    const float4* __restrict__ x4 = reinterpret_cast<const float4*>(x);
    const uint4* __restrict__ ta = ws;          // A-frags [kt*64+lane]
    const uint4* __restrict__ tv = ws + 1024;   // V'-frags [c*64+lane]

    union Frag { uint4 u4; unsigned u[4]; short8 v; };

    // ---- Xext B-frags: q0=[xh|xl], q1=[xh|1,1,0], q2/3=0 ----
    Frag B[T];
#pragma unroll
    for (int t = 0; t < T; ++t) {
        float4 xv = x4[mbase + t * 16 + ml];
        float xf[4] = {xv.x, xv.y, xv.z, xv.w};
        unsigned short xh[4], xl[4];
#pragma unroll
        for (int d = 0; d < 4; ++d) {
            xh[d] = bf16_of(xf[d]);
            xl[d] = bf16_of(xf[d] - bf16_back(xh[d]));
        }
        unsigned h01 = bcat(xh[0], xh[1]), h23 = bcat(xh[2], xh[3]);
        unsigned l01 = bcat(xl[0], xl[1]), l23 = bcat(xl[2], xl[3]);
        const unsigned ONE2 = 0x3F803F80u;      // {1.0bf16, 1.0bf16}
        B[t].u[0] = (q <= 1) ? h01 : 0;
        B[t].u[1] = (q <= 1) ? h23 : 0;
        B[t].u[2] = (q == 0) ? l01 : ((q == 1) ? ONE2 : 0);
        B[t].u[3] = (q == 0) ? l23 : 0;
    }

    floatx4 O[T];
#pragma unroll
    for (int t = 0; t < T; ++t) O[t] = (floatx4){0.f, 0.f, 0.f, 0.f};
    const floatx4 Z4 = (floatx4){0.f, 0.f, 0.f, 0.f};

    for (int c = 0; c < 8; ++c) {               // 32 centers per chunk
        Frag a0, a1, vf;
        a0.u4 = ta[(2 * c) * 64 + lane];        // coalesced 1KB/wave, L1-hot
        a1.u4 = ta[(2 * c + 1) * 64 + lane];
        vf.u4 = tv[c * 64 + lane];
#pragma unroll
        for (int t = 0; t < T; ++t) {
            floatx4 S0 = __builtin_amdgcn_mfma_f32_16x16x32_bf16(a0.v, B[t].v, Z4, 0, 0, 0);
            floatx4 S1 = __builtin_amdgcn_mfma_f32_16x16x32_bf16(a1.v, B[t].v, Z4, 0, 0, 0);
            // 3/8 on trans unit, 5/8 on main pipe — run in parallel.
            Frag p;
            p.u[0] = pack_bf16(fast_exp2(S0[0]), poly_exp2(S0[1]));
            p.u[1] = pack_bf16(poly_exp2(S0[2]), fast_exp2(S0[3]));
            p.u[2] = pack_bf16(poly_exp2(S1[0]), fast_exp2(S1[1]));
            p.u[3] = pack_bf16(poly_exp2(S1[2]), poly_exp2(S1[3]));
            O[t] = __builtin_amdgcn_mfma_f32_16x16x32_bf16(p.v, vf.v, O[t], 0, 0, 0);
        }
    }

    // ---- epilogue: D col n = lane&15, row m = q*4 + r; col 4 = denominator.
#pragma unroll
    for (int t = 0; t < T; ++t) {
#pragma unroll
        for (int r = 0; r < 4; ++r) {
            float den = __shfl(O[t][r], (lane & 48) + 4, 64);
            float val = O[t][r] * fast_rcp(den);
            int m = mbase + t * 16 + q * 4 + r;
            if (ml < 4) out[m * 4 + ml] = val;
        }
    }
}

extern "C" void kernel_launch(void* const* d_in, const int* in_sizes, int n_in,
                              void* d_out, int out_size, void* d_ws, size_t ws_size,
                              hipStream_t stream) {
    const float* x      = (const float*)d_in[0];   // [8, 262144] fp32
    const float* center = (const float*)d_in[1];   // [256, 4] fp32
    float* out = (float*)d_out;
    uint4* ws  = (uint4*)d_ws;                     // 1536 uint4 = 24 KB

    vq_prep<<<6, 256, 0, stream>>>(center, ws);

    int nvec   = in_sizes[0] / 4;                  // 524288 m-vectors
    int blocks = nvec / (4 * 16 * T);              // 4096
    vq_main<<<blocks, BLK, 0, stream>>>(x, ws, out);
}

// Round 12
// 81.767 us; speedup vs baseline: 1.1842x; 1.1207x over previous
//
#include <hip/hip_runtime.h>
#include <hip/hip_bf16.h>

#ifndef __has_builtin
#define __has_builtin(x) 0
#endif

typedef __attribute__((ext_vector_type(8))) short short8;   // 8 bf16 = 4 VGPRs
typedef __attribute__((ext_vector_type(4))) float floatx4;  // MFMA C/D

__device__ __forceinline__ float fast_exp2(float x) {
#if __has_builtin(__builtin_amdgcn_exp2f)
    return __builtin_amdgcn_exp2f(x);   // R10/R11 falsified the slow-trans theory:
#else                                    // v_exp_f32 is cheap; keep all 8 on it.
    return exp2f(x);
#endif
}
__device__ __forceinline__ float fast_rcp(float x) {
#if __has_builtin(__builtin_amdgcn_rcpf)
    return __builtin_amdgcn_rcpf(x);
#else
    return 1.0f / x;
#endif
}
__device__ __forceinline__ unsigned short bf16_of(float v) {
    union { __hip_bfloat16 b; unsigned short s; } cv;
    cv.b = __float2bfloat16(v);
    return cv.s;
}
__device__ __forceinline__ float bf16_back(unsigned short s) {
    union { __hip_bfloat16 b; unsigned short t; } cv;
    cv.t = s;
    return __bfloat162float(cv.b);
}
__device__ __forceinline__ unsigned bcat(unsigned short lo, unsigned short hi) {
    return (unsigned)lo | ((unsigned)hi << 16);   // slot j even = low half
}
__device__ __forceinline__ unsigned pack_bf16(float a, float b) {
    __hip_bfloat162 h = __float22bfloat162_rn(make_float2(a, b));
    union { __hip_bfloat162 h2; unsigned u; } cv;
    cv.h2 = h;
    return cv.u;
}

#define VQ_K 256
#define BLK  1024   // R12: 16-wave workgroups. vq_main has no LDS/barriers, so
                    // big WGs are free; 4x fewer dispatches, residency arrives
                    // in 16-wave quanta (R7 showed only ~3.4/8 waves resident
                    // with 256-thread WGs despite VGPR=32 -> placement-limited).
#define T    2

// Math identical to R9 (best): both GEMMs on MFMA via 16x16x32 bf16 —
// S^T = C2ext*Xext with 13-slot error-compensated bf16 split, weights
// p = exp2(S) packed in-lane into PV A-frags, pi-permutation baked into
// V'-frags, D col 4 = denominator. Tables built once in d_ws by vq_prep.

// ---- pre-kernel: fragment tables into d_ws (24 KB, L1-resident) ----
__global__ void vq_prep(const float* __restrict__ center, uint4* __restrict__ ws) {
    const float L2E = 1.4426950408889634f;
    int f = blockIdx.x * 256 + threadIdx.x;
    if (f < 1024) {
        int q = (f >> 4) & 3, ml = f & 15;
        int k = (f >> 6) * 16 + ml;
        float4 c = reinterpret_cast<const float4*>(center)[k];
        float s = 2.0f * L2E;
        float c2f[4] = {s * c.x, s * c.y, s * c.z, s * c.w};
        unsigned short ch[4], cl[4];
#pragma unroll
        for (int d = 0; d < 4; ++d) {
            ch[d] = bf16_of(c2f[d]);
            cl[d] = bf16_of(c2f[d] - bf16_back(ch[d]));
        }
        float b = -L2E * (c.x * c.x + c.y * c.y + c.z * c.z + c.w * c.w);
        unsigned short bh = bf16_of(b);
        unsigned short bl = bf16_of(b - bf16_back(bh));
        uint4 e;
        if (q == 0) {
            e.x = bcat(ch[0], ch[1]); e.y = bcat(ch[2], ch[3]);
            e.z = e.x;                e.w = e.y;           // d4-7 pair with xl
        } else if (q == 1) {
            e.x = bcat(cl[0], cl[1]); e.y = bcat(cl[2], cl[3]);
            e.z = bcat(bh, bl);       e.w = 0;             // d12=bh, d13=bl
        } else {
            e.x = e.y = e.z = e.w = 0;
        }
        ws[f] = e;
    } else {
        int g = f - 1024;                 // 0..511
        int c = g >> 6, q = (g >> 4) & 3, n = g & 15;
        unsigned rr[4];
#pragma unroll
        for (int r = 0; r < 4; ++r) {
            int j0 = 2 * r, j1 = 2 * r + 1;
            int k0 = 32 * c + (j0 < 4 ? 4 * q + j0 : 16 + 4 * q + j0 - 4);
            int k1 = 32 * c + (j1 < 4 ? 4 * q + j1 : 16 + 4 * q + j1 - 4);
            float v0 = (n < 4) ? center[k0 * 4 + n] : (n == 4 ? 1.f : 0.f);
            float v1 = (n < 4) ? center[k1 * 4 + n] : (n == 4 ? 1.f : 0.f);
            rr[r] = bcat(bf16_of(v0), bf16_of(v1));
        }
        ws[f] = make_uint4(rr[0], rr[1], rr[2], rr[3]);
    }
}

__global__ __launch_bounds__(BLK, 8) void vq_main(const float* __restrict__ x,
                                                  const uint4* __restrict__ ws,
                                                  float* __restrict__ out) {
    const int lane = threadIdx.x & 63;
    const int wv   = threadIdx.x >> 6;          // 0..15 waves in block
    const int q    = lane >> 4;
    const int ml   = lane & 15;
    const int mbase = blockIdx.x * (16 * 16 * T) + wv * (16 * T);
    const float4* __restrict__ x4 = reinterpret_cast<const float4*>(x);
    const uint4* __restrict__ ta = ws;          // A-frags [kt*64+lane]
    const uint4* __restrict__ tv = ws + 1024;   // V'-frags [c*64+lane]

    union Frag { uint4 u4; unsigned u[4]; short8 v; };

    // ---- Xext B-frags: q0=[xh|xl], q1=[xh|1,1,0], q2/3=0 ----
    Frag B[T];
#pragma unroll
    for (int t = 0; t < T; ++t) {
        float4 xv = x4[mbase + t * 16 + ml];
        float xf[4] = {xv.x, xv.y, xv.z, xv.w};
        unsigned short xh[4], xl[4];
#pragma unroll
        for (int d = 0; d < 4; ++d) {
            xh[d] = bf16_of(xf[d]);
            xl[d] = bf16_of(xf[d] - bf16_back(xh[d]));
        }
        unsigned h01 = bcat(xh[0], xh[1]), h23 = bcat(xh[2], xh[3]);
        unsigned l01 = bcat(xl[0], xl[1]), l23 = bcat(xl[2], xl[3]);
        const unsigned ONE2 = 0x3F803F80u;      // {1.0bf16, 1.0bf16}
        B[t].u[0] = (q <= 1) ? h01 : 0;
        B[t].u[1] = (q <= 1) ? h23 : 0;
        B[t].u[2] = (q == 0) ? l01 : ((q == 1) ? ONE2 : 0);
        B[t].u[3] = (q == 0) ? l23 : 0;
    }

    floatx4 O[T];
#pragma unroll
    for (int t = 0; t < T; ++t) O[t] = (floatx4){0.f, 0.f, 0.f, 0.f};
    const floatx4 Z4 = (floatx4){0.f, 0.f, 0.f, 0.f};

    for (int c = 0; c < 8; ++c) {               // 32 centers per chunk
        Frag a0, a1, vf;
        a0.u4 = ta[(2 * c) * 64 + lane];        // coalesced 1KB/wave, L1-hot
        a1.u4 = ta[(2 * c + 1) * 64 + lane];
        vf.u4 = tv[c * 64 + lane];
#pragma unroll
        for (int t = 0; t < T; ++t) {
            floatx4 S0 = __builtin_amdgcn_mfma_f32_16x16x32_bf16(a0.v, B[t].v, Z4, 0, 0, 0);
            floatx4 S1 = __builtin_amdgcn_mfma_f32_16x16x32_bf16(a1.v, B[t].v, Z4, 0, 0, 0);
            Frag p;
            p.u[0] = pack_bf16(fast_exp2(S0[0]), fast_exp2(S0[1]));
            p.u[1] = pack_bf16(fast_exp2(S0[2]), fast_exp2(S0[3]));
            p.u[2] = pack_bf16(fast_exp2(S1[0]), fast_exp2(S1[1]));
            p.u[3] = pack_bf16(fast_exp2(S1[2]), fast_exp2(S1[3]));
            O[t] = __builtin_amdgcn_mfma_f32_16x16x32_bf16(p.v, vf.v, O[t], 0, 0, 0);
        }
    }

    // ---- epilogue: D col n = lane&15, row m = q*4 + r; col 4 = denominator.
#pragma unroll
    for (int t = 0; t < T; ++t) {
#pragma unroll
        for (int r = 0; r < 4; ++r) {
            float den = __shfl(O[t][r], (lane & 48) + 4, 64);
            float val = O[t][r] * fast_rcp(den);
            int m = mbase + t * 16 + q * 4 + r;
            if (ml < 4) out[m * 4 + ml] = val;
        }
    }
}

extern "C" void kernel_launch(void* const* d_in, const int* in_sizes, int n_in,
                              void* d_out, int out_size, void* d_ws, size_t ws_size,
                              hipStream_t stream) {
    const float* x      = (const float*)d_in[0];   // [8, 262144] fp32
    const float* center = (const float*)d_in[1];   // [256, 4] fp32
    float* out = (float*)d_out;
    uint4* ws  = (uint4*)d_ws;                     // 1536 uint4 = 24 KB

    vq_prep<<<6, 256, 0, stream>>>(center, ws);

    int nvec   = in_sizes[0] / 4;                  // 524288 m-vectors
    int blocks = nvec / (16 * 16 * T);             // 1024 big blocks (16 waves)
    vq_main<<<blocks, BLK, 0, stream>>>(x, ws, out);
}